// Round 8
// baseline (1489.647 us; speedup 1.0000x reference)
//
#include <hip/hip_runtime.h>
#include <math.h>

typedef unsigned short u16;
typedef __attribute__((ext_vector_type(4))) float f32x4;
typedef __attribute__((ext_vector_type(8))) short bf16x8;
typedef __attribute__((ext_vector_type(8))) unsigned short u16x8;
typedef __attribute__((ext_vector_type(4))) unsigned short u16x4;

#define B_ROWS 8192
#define GLDS(gaddr, laddr)                                                                  \
  __builtin_amdgcn_global_load_lds(                                                        \
      (const __attribute__((address_space(1))) unsigned int*)(const void*)(gaddr),          \
      (__attribute__((address_space(3))) unsigned int*)(void*)(laddr), 16, 0, 0)

__device__ __forceinline__ u16 f2bf(float f) {
  unsigned int u = __float_as_uint(f);
  unsigned int r = u + 0x7fffu + ((u >> 16) & 1u);
  return (u16)(r >> 16);
}
__device__ __forceinline__ float bf2f(u16 v) {
  return __uint_as_float(((unsigned)v) << 16);
}

// inline-asm LDS read: invisible to LLVM's LDS-DMA alias tracking (rule 18).
__device__ __forceinline__ bf16x8 dsr(unsigned a) {
  bf16x8 d;
  asm volatile("ds_read_b128 %0, %1" : "=v"(d) : "v"(a));
  return d;
}

// ---------------- block-wide (256 thr) dual reduction ----------------
__device__ __forceinline__ void block_reduce2(float& a, float& b) {
  __shared__ float sb[8];
  #pragma unroll
  for (int off = 32; off > 0; off >>= 1) {
    a += __shfl_down(a, off, 64);
    b += __shfl_down(b, off, 64);
  }
  int lane = threadIdx.x & 63, wid = threadIdx.x >> 6;
  if (lane == 0) { sb[wid] = a; sb[wid + 4] = b; }
  __syncthreads();
  a = sb[0] + sb[1] + sb[2] + sb[3];
  b = sb[4] + sb[5] + sb[6] + sb[7];
  __syncthreads();
}

// ---------------- fused: LayerNorm rows (blocks 0..8191) + h->bf16 (blocks 8192..10239) ----------------
__global__ __launch_bounds__(256) void ln_cvt(const float* __restrict__ seq,
                                              const float* __restrict__ w,
                                              const float* __restrict__ b,
                                              u16* __restrict__ xbf,
                                              const float* __restrict__ h1,
                                              u16* __restrict__ hbf) {
  if (blockIdx.x < 8192) {
    int row = blockIdx.x, t = threadIdx.x;
    const f32x4* x = (const f32x4*)(seq + (size_t)row * 2048);
    f32x4 v0 = x[2 * t], v1 = x[2 * t + 1];
    float s = 0.f, q = 0.f;
    #pragma unroll
    for (int i = 0; i < 4; ++i) { s += v0[i] + v1[i]; q += v0[i] * v0[i] + v1[i] * v1[i]; }
    block_reduce2(s, q);
    float mu = s * (1.f / 2048.f);
    float var = q * (1.f / 2048.f) - mu * mu;
    float rstd = rsqrtf(var + 1e-5f);
    f32x4 w0 = ((const f32x4*)w)[2 * t], w1 = ((const f32x4*)w)[2 * t + 1];
    f32x4 b0 = ((const f32x4*)b)[2 * t], b1 = ((const f32x4*)b)[2 * t + 1];
    u16x8 o;
    #pragma unroll
    for (int i = 0; i < 4; ++i) o[i] = f2bf((v0[i] - mu) * rstd * w0[i] + b0[i]);
    #pragma unroll
    for (int i = 0; i < 4; ++i) o[4 + i] = f2bf((v1[i] - mu) * rstd * w1[i] + b1[i]);
    ((u16x8*)(xbf + (size_t)row * 2048))[t] = o;
  } else {
    int chunk = blockIdx.x - 8192;                 // 2048 chunks x 8192 elems
    const f32x4* src = (const f32x4*)(h1 + (size_t)chunk * 8192);
    u16x8* dst = (u16x8*)(hbf + (size_t)chunk * 8192);
    for (int i = threadIdx.x; i < 1024; i += 256) {
      f32x4 v0 = src[2 * i], v1 = src[2 * i + 1];
      u16x8 o;
      #pragma unroll
      for (int j = 0; j < 4; ++j) { o[j] = f2bf(v0[j]); o[4 + j] = f2bf(v1[j]); }
      dst[i] = o;
    }
  }
}

// ---------------- shared transpose tile body: out[c][r] = bf16(in[r][c]) ----------------
__device__ __forceinline__ void tr_tile(const float* in, int R, int Cc,
                                        u16* out, int ldo) {
  __shared__ float tile[32][33];
  int c0 = blockIdx.x * 32, r0 = blockIdx.y * 32;
  int tx = threadIdx.x, ty = threadIdx.y;
  #pragma unroll
  for (int j = 0; j < 4; ++j) {
    int rr = r0 + ty + j * 8;
    if (rr < R && c0 + tx < Cc) tile[ty + j * 8][tx] = in[(size_t)rr * Cc + c0 + tx];
  }
  __syncthreads();
  #pragma unroll
  for (int j = 0; j < 4; ++j) {
    int cc = c0 + ty + j * 8, rr = r0 + tx;
    if (cc < Cc && rr < R) out[(size_t)cc * ldo + rr] = f2bf(tile[tx][ty + j * 8]);
  }
}

__global__ void transpose_cvt(const float* __restrict__ in, int R, int Cc,
                              u16* __restrict__ out, int ldo) {
  tr_tile(in, R, Cc, out, ldo);
}

__global__ void transpose_gate4(const float* __restrict__ W0, const float* __restrict__ W1,
                                const float* __restrict__ W2, const float* __restrict__ W3,
                                u16* __restrict__ out) {
  int z = blockIdx.z;
  const float* in = (z == 0) ? W0 : (z == 1) ? W1 : (z == 2) ? W2 : W3;
  tr_tile(in, 2048, 2048, out + (size_t)z * 4194304, 2048);
}

__global__ void transpose_rec4(const float* __restrict__ R0, const float* __restrict__ R1,
                               const float* __restrict__ R2, const float* __restrict__ R3,
                               u16* __restrict__ out) {
  int g = blockIdx.z >> 3, hd = blockIdx.z & 7;
  const float* in = ((g == 0) ? R0 : (g == 1) ? R1 : (g == 2) ? R2 : R3) + (size_t)hd * 65536;
  tr_tile(in, 256, 256, out + (size_t)g * 524288 + (size_t)hd * 65536, 256);
}

// ---------------- bias packing ----------------
__global__ __launch_bounds__(256) void pack_bias(const float* __restrict__ bi, const float* __restrict__ bf_,
                                                 const float* __restrict__ bz, const float* __restrict__ bo,
                                                 const float* __restrict__ bup,
                                                 float* __restrict__ biasg, float* __restrict__ biasup) {
  int i = blockIdx.x * 256 + threadIdx.x;
  if (i < 8192) {
    int g = i >> 11, j = i & 2047;
    const float* p = (g == 0) ? bi : (g == 1) ? bf_ : (g == 2) ? bz : bo;
    biasg[i] = p[j];
  }
  if (i < 5504) biasup[i] = (i < 5460) ? bup[i] : 0.f;
}

#define MFMA_CLUSTER(lo, AV, BV)                                                           \
  __builtin_amdgcn_s_setprio(1);                                                           \
  _Pragma("unroll")                                                                        \
  for (int mi = 0; mi < 4; ++mi)                                                           \
    _Pragma("unroll")                                                                      \
    for (int ni = 0; ni < 4; ++ni)                                                         \
      acc[(lo) + mi][ni] =                                                                 \
          __builtin_amdgcn_mfma_f32_16x16x32_bf16(AV[mi], BV[ni], acc[(lo) + mi][ni], 0, 0, 0); \
  __builtin_amdgcn_s_setprio(0);

#define WAIT_LGKM(N)                                                                       \
  asm volatile("s_waitcnt lgkmcnt(" #N ")" ::: "memory");                                  \
  __builtin_amdgcn_sched_barrier(0);

// =====================================================================
// 256x256 tile, BK=64, 8-wave (2Mx4N) MFMA GEMM. All 20 kh0+kh1 reads
// issue up-front (LDS queue stays full through clusters 1-2); counted
// lgkm waits 12/8/4/0. Staging: kh1(t+1) at tile TOP (HBM latency hides
// under 2 clusters; safe — tile t-1's kh1 reads of that slot drained
// before its end-barrier); kh0(t+2) after the mid-barrier (overwrite of
// the kh0 region all waves just finished reading; outstanding reads at
// the mid-barrier are kh1-only by WAIT_LGKM(8)).
// vmcnt ledger (positional): enter tile with 4 outstanding; top +4, mid
// +4; end vmcnt(4) drains oldest 8 = all 4 halves of t+1; kh0(t+2) in
// flight. OB=1: C stored as bf16. Bank swizzle s' = s ^ ((row>>1)&3).
// =====================================================================
template<int REC, int OB>
__global__ __launch_bounds__(512, 2) void gemm256(
    const u16* __restrict__ A, int lda,
    const u16* __restrict__ Bt, int ldb, int KT,
    void* __restrict__ Cv, long ldc, int Nvalid, int ntN,
    const float* __restrict__ bias,
    const float* __restrict__ addsrc, int ldadd,
    const u16* __restrict__ hbf, const u16* __restrict__ RTw) {
  __shared__ __align__(16) u16 Al[2][2][256][32];
  __shared__ __align__(16) u16 Bl[2][2][256][32];
  const int NT = KT + (REC ? 4 : 0);

  int nb = gridDim.x;
  int bid = blockIdx.x;
  int per = nb >> 3;                       // grids are multiples of 8
  int id = (bid & 7) * per + (bid >> 3);   // XCD-aware swizzle (bijective)
  int m0 = (id / ntN) * 256, n0 = (id % ntN) * 256;

  int tid = threadIdx.x, lane = tid & 63, wave = tid >> 6;
  int wm = wave >> 2, wn = wave & 3;       // 2 x 4 wave grid
  int r = lane & 15, sgrp = lane >> 4;

  const u16* rsrc = nullptr; int hcol = 0;
  if (REC) {
    int g = n0 >> 11, head = (n0 & 2047) >> 8;
    rsrc = RTw + ((size_t)(g * 8 + head)) * 65536;
    hcol = head * 256;
  }

  auto stage = [&](int tt, int which) {    // which: 0=Akh0 1=Akh1 2=Bkh0 3=Bkh1
    if (tt >= NT) return;
    const int isA = (which < 2), kh = which & 1, slot = tt & 1;
    const u16* src; size_t ld;
    if (!REC || tt < KT) {
      if (isA) { src = A + (size_t)m0 * lda + tt * 64; ld = lda; }
      else     { src = Bt + (size_t)n0 * ldb + tt * 64; ld = ldb; }
    } else {
      int t2 = tt - KT;
      if (isA) { src = hbf + (size_t)m0 * 2048 + hcol + t2 * 64; ld = 2048; }
      else     { src = rsrc + t2 * 64; ld = 256; }
    }
    u16* base = isA ? &Al[slot][kh][0][0] : &Bl[slot][kh][0][0];
    #pragma unroll
    for (int c = 0; c < 2; ++c) {
      int R0 = wave * 32 + c * 16;                 // wave-uniform
      int row = R0 + (lane >> 2);
      int s = (lane & 3) ^ ((row >> 1) & 3);       // inverse-swizzled source
      GLDS(src + (size_t)row * ld + kh * 32 + s * 8, base + R0 * 32);
    }
  };

  // 32-bit LDS byte addresses for inline-asm reads
  unsigned AlB = (unsigned)(size_t)(__attribute__((address_space(3))) u16*)&Al[0][0][0][0];
  unsigned BlB = (unsigned)(size_t)(__attribute__((address_space(3))) u16*)&Bl[0][0][0][0];
  int sA = sgrp ^ ((r >> 1) & 3);                  // row&15 == r for all frag rows
  unsigned aBaseT = AlB + (unsigned)((wm * 128 + r) * 64 + sA * 16);
  unsigned bBaseT = BlB + (unsigned)((wn * 64 + r) * 64 + sA * 16);

  f32x4 acc[8][4] = {};
  bf16x8 a0[4], a1[4], a2[4], a3[4], b0[4], b1[4];

  // ---- prologue: tile0 (4 halves) + tile1 {Akh0,Bkh0} ----
  stage(0, 0); stage(0, 2); stage(0, 1); stage(0, 3);
  stage(1, 0); stage(1, 2);
  asm volatile("s_waitcnt vmcnt(4)" ::: "memory");
  __builtin_amdgcn_s_barrier();

  for (int t = 0; t < NT; ++t) {
    unsigned sl = (unsigned)(t & 1) * 32768u;
    unsigned ab = aBaseT + sl, bb = bBaseT + sl;
    __builtin_amdgcn_sched_barrier(0);
    // stage next tile's kh1 halves first (HBM latency hides under clusters)
    stage(t + 1, 1); stage(t + 1, 3);
    // ---- burst1: kh0 reads (12) ----
    a0[0] = dsr(ab);          a0[1] = dsr(ab + 1024);
    a0[2] = dsr(ab + 2048);   a0[3] = dsr(ab + 3072);
    b0[0] = dsr(bb);          b0[1] = dsr(bb + 1024);
    b0[2] = dsr(bb + 2048);   b0[3] = dsr(bb + 3072);
    a1[0] = dsr(ab + 4096);   a1[1] = dsr(ab + 5120);
    a1[2] = dsr(ab + 6144);   a1[3] = dsr(ab + 7168);
    // ---- burst2: kh1 reads (8) — queue stays full through clusters 1-2 ----
    a2[0] = dsr(ab + 16384);  a2[1] = dsr(ab + 17408);
    a2[2] = dsr(ab + 18432);  a2[3] = dsr(ab + 19456);
    b1[0] = dsr(bb + 16384);  b1[1] = dsr(bb + 17408);
    b1[2] = dsr(bb + 18432);  b1[3] = dsr(bb + 19456);
    // ---- cluster1: a0 x b0 (oldest 8 drained) ----
    WAIT_LGKM(12);
    MFMA_CLUSTER(0, a0, b0);
    // ---- cluster2: a1 x b0 ----
    WAIT_LGKM(8);
    MFMA_CLUSTER(4, a1, b0);
    __builtin_amdgcn_s_barrier();            // all waves' kh0 reads complete
    __builtin_amdgcn_sched_barrier(0);
    // safe to overwrite kh0 of current slot (outstanding reads are kh1 only)
    stage(t + 2, 0); stage(t + 2, 2);
    // ---- burst3: a3 (4) ----
    a3[0] = dsr(ab + 20480);  a3[1] = dsr(ab + 21504);
    a3[2] = dsr(ab + 22528);  a3[3] = dsr(ab + 23552);
    // ---- cluster3: a2 x b1 ----
    WAIT_LGKM(4);
    MFMA_CLUSTER(0, a2, b1);
    // ---- cluster4: a3 x b1 ----
    WAIT_LGKM(0);
    MFMA_CLUSTER(4, a3, b1);
    if (t + 2 < NT)      { asm volatile("s_waitcnt vmcnt(4)" ::: "memory"); }
    else if (t + 1 < NT) { asm volatile("s_waitcnt vmcnt(0)" ::: "memory"); }
    __builtin_amdgcn_s_barrier();
  }

  // ---- epilogue ----
  #pragma unroll
  for (int a = 0; a < 8; ++a) {
    int row0 = m0 + wm * 128 + a * 16 + sgrp * 4;
    #pragma unroll
    for (int ni = 0; ni < 4; ++ni) {
      int col = n0 + wn * 64 + ni * 16 + r;
      if (col >= Nvalid) continue;
      float bv = bias ? bias[col] : 0.f;
      #pragma unroll
      for (int jj = 0; jj < 4; ++jj) {
        float v = acc[a][ni][jj] + bv;
        if (addsrc) v += addsrc[(size_t)(row0 + jj) * ldadd + col];
        if (OB) ((u16*)Cv)[(size_t)(row0 + jj) * ldc + col] = f2bf(v);
        else    ((float*)Cv)[(size_t)(row0 + jj) * ldc + col] = v;
      }
    }
  }
}

// ---------------- sLSTM pointwise + GroupNorm v2: block=row, wave=head, no barriers ----------------
__global__ __launch_bounds__(512) void pointwise_gn(
    const float* __restrict__ G, const float* __restrict__ c1, const float* __restrict__ n1,
    const float* __restrict__ m1, const float* __restrict__ gnw, const float* __restrict__ gnb,
    float* __restrict__ outc, float* __restrict__ outn, float* __restrict__ outh,
    float* __restrict__ outm, u16* __restrict__ gnbf) {
  int b = blockIdx.x;
  int w = threadIdx.x >> 6, l = threadIdx.x & 63;
  int j = (w << 8) + l * 4;                       // 4 elems per lane, wave owns one head
  size_t rg = (size_t)b * 8192;
  f32x4 it = *(const f32x4*)(G + rg + j);
  f32x4 ft = *(const f32x4*)(G + rg + 2048 + j);
  f32x4 zt = *(const f32x4*)(G + rg + 4096 + j);
  f32x4 ot = *(const f32x4*)(G + rg + 6144 + j);
  size_t idx = (size_t)b * 2048 + j;
  f32x4 cp = *(const f32x4*)(c1 + idx);
  f32x4 np = *(const f32x4*)(n1 + idx);
  f32x4 mp = *(const f32x4*)(m1 + idx);
  f32x4 ct, nt, ht, mt;
  float s = 0.f, q = 0.f;
  #pragma unroll
  for (int i = 0; i < 4; ++i) {
    float m_ = fmaxf(ft[i] + mp[i], it[i]);
    float ig = expf(it[i] - m_), fg = expf(ft[i] - m_ + mp[i]);
    float zg = tanhf(zt[i]), og = 1.f / (1.f + expf(-ot[i]));
    ct[i] = fg * cp[i] + ig * zg;
    nt[i] = fg * np[i] + ig;
    ht[i] = og * (ct[i] / nt[i]);
    mt[i] = m_;
    s += ht[i]; q += ht[i] * ht[i];
  }
  *(f32x4*)(outc + idx) = ct;
  *(f32x4*)(outn + idx) = nt;
  *(f32x4*)(outh + idx) = ht;
  *(f32x4*)(outm + idx) = mt;
  #pragma unroll
  for (int off = 32; off > 0; off >>= 1) {
    s += __shfl_xor(s, off, 64);
    q += __shfl_xor(q, off, 64);
  }
  float mu = s * (1.f / 256.f);
  float var = q * (1.f / 256.f) - mu * mu;
  float rs = rsqrtf(var + 1e-5f);
  f32x4 gw = *(const f32x4*)(gnw + j), gb = *(const f32x4*)(gnb + j);
  u16x4 o;
  #pragma unroll
  for (int i = 0; i < 4; ++i) o[i] = f2bf((ht[i] - mu) * rs * gw[i] + gb[i]);
  *(u16x4*)(gnbf + idx) = o;
}

// ---------------- out1 + gelu(out2) from bf16 TMP, zero-pad K to 2752 (block=row) ----------------
__global__ __launch_bounds__(256) void act_gelu(const u16* __restrict__ tmp, u16* __restrict__ gl) {
  int b = blockIdx.x;
  const u16* row = tmp + (size_t)b * 5504;
  u16* orow = gl + (size_t)b * 2752;
  for (int p = threadIdx.x * 2; p < 2752; p += 512) {
    float y0 = 0.f, y1 = 0.f;
    if (p < 2730) {                                // p even, 2730 even -> p+1 < 2730
      float x10 = bf2f(row[p]), x11 = bf2f(row[p + 1]);
      float x20 = bf2f(row[2730 + p]), x21 = bf2f(row[2731 + p]);
      y0 = x10 + x20 * 0.5f * (1.f + erff(x20 * 0.70710678118f));
      y1 = x11 + x21 * 0.5f * (1.f + erff(x21 * 0.70710678118f));
    }
    orow[p] = f2bf(y0);
    orow[p + 1] = f2bf(y1);
  }
}

extern "C" void kernel_launch(void* const* d_in, const int* in_sizes, int n_in,
                              void* d_out, int out_size, void* d_ws, size_t ws_size,
                              hipStream_t stream) {
  (void)in_sizes; (void)n_in; (void)out_size; (void)ws_size;
  const float* seq = (const float*)d_in[0];
  const float* c1  = (const float*)d_in[1];
  const float* n1  = (const float*)d_in[2];
  const float* h1  = (const float*)d_in[3];
  const float* m1  = (const float*)d_in[4];
  const float* lnw = (const float*)d_in[5];
  const float* lnb = (const float*)d_in[6];
  const float* gnw = (const float*)d_in[7];
  const float* gnb = (const float*)d_in[8];
  const float* Wi = (const float*)d_in[9];  const float* bi  = (const float*)d_in[10];
  const float* Wf = (const float*)d_in[11]; const float* bf_ = (const float*)d_in[12];
  const float* Wz = (const float*)d_in[13]; const float* bz  = (const float*)d_in[14];
  const float* Wo = (const float*)d_in[15]; const float* bo  = (const float*)d_in[16];
  const float* Ri = (const float*)d_in[17]; const float* Rf = (const float*)d_in[18];
  const float* Rz = (const float*)d_in[19]; const float* Ro = (const float*)d_in[20];
  const float* Wup = (const float*)d_in[21]; const float* bup = (const float*)d_in[22];
  const float* Wdn = (const float*)d_in[23]; const float* bdn = (const float*)d_in[24];

  // ---- workspace layout (peak ~475 MB, with reuse) ----
  size_t off = 0;
  char* base = (char*)d_ws;
  auto alloc = [&](size_t bytes) { char* p = base + off; off += (bytes + 255) & ~(size_t)255; return p; };
  u16*   XBF    = (u16*)  alloc((size_t)B_ROWS * 2048 * 2);
  u16*   HBF    = (u16*)  alloc((size_t)B_ROWS * 2048 * 2);
  u16*   WGT    = (u16*)  alloc((size_t)4 * 2048 * 2048 * 2);   // gate weights, B^T
  u16*   RT     = (u16*)  alloc((size_t)4 * 8 * 256 * 256 * 2); // recurrent, B^T per head
  u16*   WUPT   = (u16*)  alloc((size_t)5632 * 2048 * 2);       // N padded to 22*256
  u16*   WDNT   = (u16*)  alloc((size_t)2048 * 2752 * 2);
  float* BIASG  = (float*)alloc((size_t)8192 * 4);
  float* BIASUP = (float*)alloc((size_t)5504 * 4);
  u16*   GNBF   = (u16*)  alloc((size_t)B_ROWS * 2048 * 2);
  float* G      = (float*)alloc((size_t)B_ROWS * 8192 * 4);
  u16*   TMP    = (u16*)G;      // reuse: G dead after pointwise_gn (90 MB <= 268 MB), bf16
  u16*   GL     = WGT;          // reuse: WGT dead after gates GEMM (45 MB <= 67 MB)

  float* OUT  = (float*)d_out;
  float* OUTC = OUT + (size_t)B_ROWS * 2048;
  float* OUTN = OUTC + (size_t)B_ROWS * 2048;
  float* OUTH = OUTN + (size_t)B_ROWS * 2048;
  float* OUTM = OUTH + (size_t)B_ROWS * 2048;

  dim3 tb32(32, 8);

  // 1) LayerNorm -> bf16  +  h_tm1 -> bf16 (fused)
  ln_cvt<<<8192 + 2048, 256, 0, stream>>>(seq, lnw, lnb, XBF, h1, HBF);
  // 2) weight transposes -> bf16 B^T layouts (batched)
  transpose_gate4<<<dim3(64, 64, 4), tb32, 0, stream>>>(Wi, Wf, Wz, Wo, WGT);
  transpose_rec4<<<dim3(8, 8, 32), tb32, 0, stream>>>(Ri, Rf, Rz, Ro, RT);
  transpose_cvt<<<dim3(171, 64, 1), tb32, 0, stream>>>(Wup, 2048, 5460, WUPT, 2048);
  transpose_cvt<<<dim3(64, 86, 1), tb32, 0, stream>>>(Wdn, 2730, 2048, WDNT, 2752);
  // 3) biases
  pack_bias<<<32, 256, 0, stream>>>(bi, bf_, bz, bo, bup, BIASG, BIASUP);
  // 4) gates GEMM: G[b, g*2048+n] = x@W_g + b_g + h@R_g (block-diag fused as 4 extra K-tiles)
  gemm256<1, 0><<<32 * 32, 512, 0, stream>>>(XBF, 2048, WGT, 2048, 32,
                                             G, 8192, 8192, 32, BIASG, nullptr, 0, HBF, RT);
  // 5) sLSTM pointwise + GroupNorm; writes c,n,h,m states + bf16 activation
  pointwise_gn<<<B_ROWS, 512, 0, stream>>>(G, c1, n1, m1, gnw, gnb,
                                           OUTC, OUTN, OUTH, OUTM, GNBF);
  // 6) up GEMM -> bf16 TMP (N tiles 22 -> 5632, stores guarded at 5460; row stride 5504)
  gemm256<0, 1><<<32 * 22, 512, 0, stream>>>(GNBF, 2048, WUPT, 2048, 32,
                                             TMP, 5504, 5460, 22, BIASUP, nullptr, 0, nullptr, nullptr);
  // 7) out1 + gelu(out2) -> bf16 (K padded 2730->2752 with zeros)
  act_gelu<<<8192, 256, 0, stream>>>(TMP, GL);
  // 8) down GEMM + b_dn + seq residual -> out
  gemm256<0, 0><<<32 * 8, 512, 0, stream>>>(GL, 2752, WDNT, 2752, 43,
                                            OUT, 2048, 2048, 8, bdn, seq, 2048, nullptr, nullptr);
}